// Round 1
// baseline (447.332 us; speedup 1.0000x reference)
//
#include <hip/hip_runtime.h>
#include <hip/hip_bf16.h>
#include <stdint.h>

#define N_TOK 2048
#define H_DIM 1024
#define F_DIM 2816
#define N_EXP 8
#define NSLOT (N_TOK * 2)

#define BK 64
#define LDA 72   // padded LDS row stride in bf16 elems (+8 keeps 16B align, breaks pow2 bank stride)
#define KSPLIT 2
#define KHALF (F_DIM / KSPLIT)   // 1408

typedef __attribute__((ext_vector_type(8))) short bf16x8;
typedef __attribute__((ext_vector_type(4))) float f32x4;

static __device__ __forceinline__ unsigned short f2bf(float f) {
    union { float f; unsigned u; } v; v.f = f;
    unsigned r = v.u + 0x7fffu + ((v.u >> 16) & 1u);   // round-to-nearest-even
    return (unsigned short)(r >> 16);
}

// ---------------- Router: 1 wave per token ----------------
__global__ __launch_bounds__(256) void router_kernel(
    const float* __restrict__ x, const float* __restrict__ gate_w,
    int* __restrict__ counts, int* __restrict__ row_token, float* __restrict__ row_weight,
    int* __restrict__ slot_e, int* __restrict__ slot_pos)
{
    __shared__ float gsm[N_EXP * H_DIM];
    for (int i = threadIdx.x; i < N_EXP * H_DIM; i += 256) gsm[i] = gate_w[i];
    __syncthreads();

    const int wave = threadIdx.x >> 6;
    const int lane = threadIdx.x & 63;
    const int n = blockIdx.x * 4 + wave;
    if (n >= N_TOK) return;

    float xv[16];
#pragma unroll
    for (int i = 0; i < 16; i++) xv[i] = x[(size_t)n * H_DIM + lane + 64 * i];

    float logit[N_EXP];
#pragma unroll
    for (int e = 0; e < N_EXP; e++) {
        float p = 0.f;
#pragma unroll
        for (int i = 0; i < 16; i++) p += xv[i] * gsm[e * H_DIM + lane + 64 * i];
#pragma unroll
        for (int s = 32; s > 0; s >>= 1) p += __shfl_xor(p, s, 64);
        logit[e] = p;
    }

    if (lane == 0) {
        int e0 = 0; float l0 = logit[0];
#pragma unroll
        for (int e = 1; e < N_EXP; e++) if (logit[e] > l0) { l0 = logit[e]; e0 = e; }
        int e1 = -1; float l1 = -3.4e38f;
#pragma unroll
        for (int e = 0; e < N_EXP; e++) if (e != e0 && logit[e] > l1) { l1 = logit[e]; e1 = e; }
        float w0 = 1.f / (1.f + __expf(l1 - l0));
        float w1 = 1.f - w0;
        int p0 = atomicAdd(&counts[e0], 1);
        int p1 = atomicAdd(&counts[e1], 1);
        row_token[e0 * N_TOK + p0] = n;  row_weight[e0 * N_TOK + p0] = w0;
        row_token[e1 * N_TOK + p1] = n;  row_weight[e1 * N_TOK + p1] = w1;
        slot_e[n * 2 + 0] = e0;  slot_pos[n * 2 + 0] = p0;
        slot_e[n * 2 + 1] = e1;  slot_pos[n * 2 + 1] = p1;
    }
}

// ---------------- Scan: exclusive prefix over 8 counts ----------------
__global__ void scan_kernel(const int* __restrict__ counts, int* __restrict__ offsets)
{
    if (threadIdx.x == 0 && blockIdx.x == 0) {
        int acc = 0;
        for (int e = 0; e < N_EXP; e++) { offsets[e] = acc; acc += counts[e]; }
    }
}

// ---------------- Up GEMM (grouped, double-buffered): act = silu(X @ w1[e]^T) ----
__global__ __launch_bounds__(256, 2) void up_gemm_kernel(
    const float* __restrict__ x, const float* __restrict__ w1,
    const int* __restrict__ counts, const int* __restrict__ offsets,
    const int* __restrict__ row_token,
    unsigned short* __restrict__ act)
{
    const int e = blockIdx.z;
    const int cnt = counts[e];
    const int mTile = blockIdx.y;
    if (mTile * 128 >= cnt) return;
    const int fTile = blockIdx.x;
    const int off = offsets[e];

    __shared__ __align__(16) unsigned short As[2][128 * LDA];
    __shared__ __align__(16) unsigned short Bs[2][128 * LDA];

    const int tid = threadIdx.x;
    const int lane = tid & 63;
    const int wave = tid >> 6;
    const int wm = (wave >> 1) * 64, wn = (wave & 1) * 64;

    int tokens[8];
#pragma unroll
    for (int j = 0; j < 8; j++) {
        int i = tid + 256 * j;
        int row = i >> 4;
        int pos = mTile * 128 + row;
        tokens[j] = row_token[e * N_TOK + min(pos, cnt - 1)];
    }

    f32x4 acc[4][4];
#pragma unroll
    for (int i = 0; i < 4; i++)
#pragma unroll
        for (int j = 0; j < 4; j++) acc[i][j] = (f32x4)(0.f);

    const float* wbase = w1 + (size_t)e * F_DIM * H_DIM + (size_t)(fTile * 128) * H_DIM;

    // prologue: load tile 0 into regs
    float4 areg[8], breg[8];
#pragma unroll
    for (int j = 0; j < 8; j++) {
        int i = tid + 256 * j;
        int row = i >> 4, c = i & 15;
        areg[j] = *(const float4*)(x + (size_t)tokens[j] * H_DIM + c * 4);
        breg[j] = *(const float4*)(wbase + (size_t)row * H_DIM + c * 4);
    }

    const int NKT = H_DIM / BK;   // 16
    for (int kt = 0; kt < NKT; kt++) {
        const int cur = kt & 1;
        // regs -> LDS[cur] (fp32->bf16)
#pragma unroll
        for (int j = 0; j < 8; j++) {
            int i = tid + 256 * j;
            int row = i >> 4, c = i & 15;
            float4 va = areg[j];
            ushort4 a4; a4.x = f2bf(va.x); a4.y = f2bf(va.y); a4.z = f2bf(va.z); a4.w = f2bf(va.w);
            *(ushort4*)(As[cur] + row * LDA + c * 4) = a4;
            float4 vb = breg[j];
            ushort4 b4; b4.x = f2bf(vb.x); b4.y = f2bf(vb.y); b4.z = f2bf(vb.z); b4.w = f2bf(vb.w);
            *(ushort4*)(Bs[cur] + row * LDA + c * 4) = b4;
        }
        __syncthreads();
        // issue next tile's loads; they fly under the MFMA cluster below
        if (kt + 1 < NKT) {
            const int k0 = (kt + 1) * BK;
#pragma unroll
            for (int j = 0; j < 8; j++) {
                int i = tid + 256 * j;
                int row = i >> 4, c = i & 15;
                areg[j] = *(const float4*)(x + (size_t)tokens[j] * H_DIM + k0 + c * 4);
                breg[j] = *(const float4*)(wbase + (size_t)row * H_DIM + k0 + c * 4);
            }
        }
#pragma unroll
        for (int kk = 0; kk < BK / 32; kk++) {
            const int kloc = kk * 32 + (lane >> 4) * 8;
            bf16x8 af[4], bfr[4];
#pragma unroll
            for (int i = 0; i < 4; i++)
                af[i] = *(const bf16x8*)(As[cur] + (wm + i * 16 + (lane & 15)) * LDA + kloc);
#pragma unroll
            for (int i = 0; i < 4; i++)
                bfr[i] = *(const bf16x8*)(Bs[cur] + (wn + i * 16 + (lane & 15)) * LDA + kloc);
#pragma unroll
            for (int i = 0; i < 4; i++)
#pragma unroll
                for (int j = 0; j < 4; j++)
                    acc[i][j] = __builtin_amdgcn_mfma_f32_16x16x32_bf16(af[i], bfr[j], acc[i][j], 0, 0, 0);
        }
        // no trailing barrier: next iteration writes the OTHER buffer; the
        // write of THIS buffer (kt+2) is ordered after barrier(kt+1), by which
        // time every wave has finished its kt reads (program order).
    }

    // epilogue: silu + bf16 store (C/D layout: col=lane&15, row=(lane>>4)*4+reg)
#pragma unroll
    for (int i = 0; i < 4; i++) {
        const int mrow = wm + i * 16 + ((lane >> 4) << 2);
#pragma unroll
        for (int r = 0; r < 4; r++) {
            const int m = mTile * 128 + mrow + r;
            if (m < cnt) {
#pragma unroll
                for (int j = 0; j < 4; j++) {
                    float v = acc[i][j][r];
                    float s = v / (1.f + __expf(-v));
                    int col = fTile * 128 + wn + j * 16 + (lane & 15);
                    act[(size_t)(off + m) * F_DIM + col] = f2bf(s);
                }
            }
        }
    }
}

// ---------------- Down GEMM (grouped, split-K=2, double-buffered) -------------
__global__ __launch_bounds__(256, 2) void down_gemm_kernel(
    const unsigned short* __restrict__ act, const float* __restrict__ w2,
    const int* __restrict__ counts, const int* __restrict__ offsets,
    const float* __restrict__ row_weight,
    float* __restrict__ out_partial)   // [KSPLIT][NSLOT][H_DIM]
{
    const int e  = blockIdx.z & (N_EXP - 1);
    const int ks = blockIdx.z >> 3;
    const int cnt = counts[e];
    const int mTile = blockIdx.y;
    if (mTile * 128 >= cnt) return;
    const int hTile = blockIdx.x;
    const int off = offsets[e];

    __shared__ __align__(16) unsigned short As[2][128 * LDA];
    __shared__ __align__(16) unsigned short Bs[2][128 * LDA];

    const int tid = threadIdx.x;
    const int lane = tid & 63;
    const int wave = tid >> 6;
    const int wm = (wave >> 1) * 64, wn = (wave & 1) * 64;

    int rowsg[4];
#pragma unroll
    for (int j = 0; j < 4; j++) {
        int i = tid + 256 * j;
        int row = i >> 3;
        rowsg[j] = off + min(mTile * 128 + row, cnt - 1);
    }

    f32x4 acc[4][4];
#pragma unroll
    for (int i = 0; i < 4; i++)
#pragma unroll
        for (int j = 0; j < 4; j++) acc[i][j] = (f32x4)(0.f);

    const float* wbase = w2 + (size_t)e * H_DIM * F_DIM + (size_t)(hTile * 128) * F_DIM;
    const int kbase = ks * KHALF;
    const int NKT = KHALF / BK;   // 22

    // prologue: load tile 0 into regs
    uint4 areg[4]; float4 breg[8];
#pragma unroll
    for (int j = 0; j < 4; j++) {
        int i = tid + 256 * j;
        int c = i & 7;
        areg[j] = *(const uint4*)(act + (size_t)rowsg[j] * F_DIM + kbase + c * 8);
    }
#pragma unroll
    for (int j = 0; j < 8; j++) {
        int i = tid + 256 * j;
        int row = i >> 4, c = i & 15;
        breg[j] = *(const float4*)(wbase + (size_t)row * F_DIM + kbase + c * 4);
    }

    for (int kt = 0; kt < NKT; kt++) {
        const int cur = kt & 1;
#pragma unroll
        for (int j = 0; j < 4; j++) {            // A: bf16 act, direct 16B copy
            int i = tid + 256 * j;
            int row = i >> 3, c = i & 7;
            *(uint4*)(As[cur] + row * LDA + c * 8) = areg[j];
        }
#pragma unroll
        for (int j = 0; j < 8; j++) {            // B: w2 fp32->bf16
            int i = tid + 256 * j;
            int row = i >> 4, c = i & 15;
            float4 v = breg[j];
            ushort4 b4; b4.x = f2bf(v.x); b4.y = f2bf(v.y); b4.z = f2bf(v.z); b4.w = f2bf(v.w);
            *(ushort4*)(Bs[cur] + row * LDA + c * 4) = b4;
        }
        __syncthreads();
        if (kt + 1 < NKT) {
            const int k0 = kbase + (kt + 1) * BK;
#pragma unroll
            for (int j = 0; j < 4; j++) {
                int i = tid + 256 * j;
                int c = i & 7;
                areg[j] = *(const uint4*)(act + (size_t)rowsg[j] * F_DIM + k0 + c * 8);
            }
#pragma unroll
            for (int j = 0; j < 8; j++) {
                int i = tid + 256 * j;
                int row = i >> 4, c = i & 15;
                breg[j] = *(const float4*)(wbase + (size_t)row * F_DIM + k0 + c * 4);
            }
        }
#pragma unroll
        for (int kk = 0; kk < BK / 32; kk++) {
            const int kloc = kk * 32 + (lane >> 4) * 8;
            bf16x8 af[4], bfr[4];
#pragma unroll
            for (int i = 0; i < 4; i++)
                af[i] = *(const bf16x8*)(As[cur] + (wm + i * 16 + (lane & 15)) * LDA + kloc);
#pragma unroll
            for (int i = 0; i < 4; i++)
                bfr[i] = *(const bf16x8*)(Bs[cur] + (wn + i * 16 + (lane & 15)) * LDA + kloc);
#pragma unroll
            for (int i = 0; i < 4; i++)
#pragma unroll
                for (int j = 0; j < 4; j++)
                    acc[i][j] = __builtin_amdgcn_mfma_f32_16x16x32_bf16(af[i], bfr[j], acc[i][j], 0, 0, 0);
        }
    }

    float* obase = out_partial + (size_t)ks * NSLOT * H_DIM;
#pragma unroll
    for (int i = 0; i < 4; i++) {
        const int mrow = wm + i * 16 + ((lane >> 4) << 2);
#pragma unroll
        for (int r = 0; r < 4; r++) {
            const int m = mTile * 128 + mrow + r;
            if (m < cnt) {
                const float w = row_weight[e * N_TOK + m];
#pragma unroll
                for (int j = 0; j < 4; j++) {
                    int col = hTile * 128 + wn + j * 16 + (lane & 15);
                    obase[(size_t)(off + m) * H_DIM + col] = w * acc[i][j][r];
                }
            }
        }
    }
}

// ---------------- Combine: y[n] = sum over 2 slots x 2 K-splits ---------------
__global__ __launch_bounds__(256) void combine_kernel(
    const float* __restrict__ out_partial, const int* __restrict__ offsets,
    const int* __restrict__ slot_e, const int* __restrict__ slot_pos,
    float* __restrict__ out)
{
    const int n = blockIdx.x;
    const int r0 = offsets[slot_e[n * 2 + 0]] + slot_pos[n * 2 + 0];
    const int r1 = offsets[slot_e[n * 2 + 1]] + slot_pos[n * 2 + 1];
    const int t = threadIdx.x;
    const float* p0 = out_partial;
    const float* p1 = out_partial + (size_t)NSLOT * H_DIM;
    const float4 a = *(const float4*)(p0 + (size_t)r0 * H_DIM + t * 4);
    const float4 b = *(const float4*)(p1 + (size_t)r0 * H_DIM + t * 4);
    const float4 c = *(const float4*)(p0 + (size_t)r1 * H_DIM + t * 4);
    const float4 d = *(const float4*)(p1 + (size_t)r1 * H_DIM + t * 4);
    float4 s;
    s.x = (a.x + b.x) + (c.x + d.x);
    s.y = (a.y + b.y) + (c.y + d.y);
    s.z = (a.z + b.z) + (c.z + d.z);
    s.w = (a.w + b.w) + (c.w + d.w);
    *(float4*)(out + (size_t)n * H_DIM + t * 4) = s;
}

extern "C" void kernel_launch(void* const* d_in, const int* in_sizes, int n_in,
                              void* d_out, int out_size, void* d_ws, size_t ws_size,
                              hipStream_t stream) {
    const float* x      = (const float*)d_in[0];
    const float* gate_w = (const float*)d_in[1];
    const float* w1     = (const float*)d_in[2];
    const float* w2     = (const float*)d_in[3];
    float* out = (float*)d_out;

    char* ws = (char*)d_ws;
    size_t o = 0;
    auto alloc = [&](size_t bytes) -> void* {
        void* p = ws + o;
        o = (o + bytes + 255) & ~(size_t)255;
        return p;
    };
    int*   counts     = (int*)  alloc(N_EXP * sizeof(int));
    int*   offsets    = (int*)  alloc(N_EXP * sizeof(int));
    int*   row_token  = (int*)  alloc((size_t)N_EXP * N_TOK * sizeof(int));
    float* row_weight = (float*)alloc((size_t)N_EXP * N_TOK * sizeof(float));
    int*   slot_e     = (int*)  alloc((size_t)N_TOK * 2 * sizeof(int));
    int*   slot_pos   = (int*)  alloc((size_t)N_TOK * 2 * sizeof(int));
    unsigned short* act = (unsigned short*)alloc((size_t)NSLOT * F_DIM * sizeof(unsigned short));
    float* out_partial = (float*)alloc((size_t)KSPLIT * NSLOT * H_DIM * sizeof(float));

    hipMemsetAsync(counts, 0, N_EXP * sizeof(int), stream);

    router_kernel<<<N_TOK / 4, 256, 0, stream>>>(x, gate_w, counts, row_token, row_weight, slot_e, slot_pos);
    scan_kernel<<<1, 64, 0, stream>>>(counts, offsets);
    up_gemm_kernel<<<dim3(F_DIM / 128, N_TOK / 128, N_EXP), 256, 0, stream>>>(
        x, w1, counts, offsets, row_token, act);
    down_gemm_kernel<<<dim3(H_DIM / 128, N_TOK / 128, N_EXP * KSPLIT), 256, 0, stream>>>(
        act, w2, counts, offsets, row_weight, out_partial);
    combine_kernel<<<N_TOK, 256, 0, stream>>>(out_partial, offsets, slot_e, slot_pos, out);
}

// Round 2
// 391.736 us; speedup vs baseline: 1.1419x; 1.1419x over previous
//
#include <hip/hip_runtime.h>
#include <stdint.h>

#define N_TOK 2048
#define H_DIM 1024
#define F_DIM 2816
#define N_EXP 8
#define NSLOT (N_TOK * 2)

#define BK 64
#define KSPLIT 2
#define KHALF (F_DIM / KSPLIT)   // 1408

#define N8_X (N_TOK * H_DIM / 8)          // 262144
#define N8_W (N_EXP * F_DIM * H_DIM / 8)  // 2883584

typedef __attribute__((ext_vector_type(8))) short bf16x8;
typedef __attribute__((ext_vector_type(4))) float f32x4;

typedef __attribute__((address_space(1))) unsigned int gu32;
typedef __attribute__((address_space(3))) unsigned int lu32;

static __device__ __forceinline__ unsigned short f2bf(float f) {
    union { float f; unsigned u; } v; v.f = f;
    unsigned r = v.u + 0x7fffu + ((v.u >> 16) & 1u);   // round-to-nearest-even
    return (unsigned short)(r >> 16);
}

// async 16B/lane global->LDS; LDS dest must be wave-uniform base (lane*16 implicit)
static __device__ __forceinline__ void gload16(const unsigned short* g, unsigned short* l) {
    __builtin_amdgcn_global_load_lds((const gu32*)g, (lu32*)l, 16, 0, 0);
}

// ---------------- Convert: fp32 -> bf16 for x, w1, w2 (one dispatch) ----------
__global__ __launch_bounds__(256) void convert_all_kernel(
    const float* __restrict__ x, const float* __restrict__ w1, const float* __restrict__ w2,
    unsigned short* __restrict__ x_bf, unsigned short* __restrict__ w1_bf, unsigned short* __restrict__ w2_bf)
{
    const int total = N8_X + 2 * N8_W;
    int i = blockIdx.x * 256 + threadIdx.x;
    const int stride = gridDim.x * 256;
    for (; i < total; i += stride) {
        const float* src; unsigned short* dst; size_t k;
        if (i < N8_X)            { src = x;  dst = x_bf;  k = i; }
        else if (i < N8_X + N8_W){ src = w1; dst = w1_bf; k = i - N8_X; }
        else                     { src = w2; dst = w2_bf; k = i - N8_X - N8_W; }
        const float4 a = *(const float4*)(src + k * 8);
        const float4 b = *(const float4*)(src + k * 8 + 4);
        ushort4 lo, hi;
        lo.x = f2bf(a.x); lo.y = f2bf(a.y); lo.z = f2bf(a.z); lo.w = f2bf(a.w);
        hi.x = f2bf(b.x); hi.y = f2bf(b.y); hi.z = f2bf(b.z); hi.w = f2bf(b.w);
        uint4 out;
        out.x = (unsigned)lo.x | ((unsigned)lo.y << 16);
        out.y = (unsigned)lo.z | ((unsigned)lo.w << 16);
        out.z = (unsigned)hi.x | ((unsigned)hi.y << 16);
        out.w = (unsigned)hi.z | ((unsigned)hi.w << 16);
        *(uint4*)(dst + k * 8) = out;
    }
}

// ---------------- Router: 1 wave per token ----------------
__global__ __launch_bounds__(256) void router_kernel(
    const float* __restrict__ x, const float* __restrict__ gate_w,
    int* __restrict__ counts, int* __restrict__ row_token, float* __restrict__ row_weight,
    int* __restrict__ slot_e, int* __restrict__ slot_pos)
{
    __shared__ float gsm[N_EXP * H_DIM];
    for (int i = threadIdx.x; i < N_EXP * H_DIM; i += 256) gsm[i] = gate_w[i];
    __syncthreads();

    const int wave = threadIdx.x >> 6;
    const int lane = threadIdx.x & 63;
    const int n = blockIdx.x * 4 + wave;
    if (n >= N_TOK) return;

    float xv[16];
#pragma unroll
    for (int i = 0; i < 16; i++) xv[i] = x[(size_t)n * H_DIM + lane + 64 * i];

    float logit[N_EXP];
#pragma unroll
    for (int e = 0; e < N_EXP; e++) {
        float p = 0.f;
#pragma unroll
        for (int i = 0; i < 16; i++) p += xv[i] * gsm[e * H_DIM + lane + 64 * i];
#pragma unroll
        for (int s = 32; s > 0; s >>= 1) p += __shfl_xor(p, s, 64);
        logit[e] = p;
    }

    if (lane == 0) {
        int e0 = 0; float l0 = logit[0];
#pragma unroll
        for (int e = 1; e < N_EXP; e++) if (logit[e] > l0) { l0 = logit[e]; e0 = e; }
        int e1 = -1; float l1 = -3.4e38f;
#pragma unroll
        for (int e = 0; e < N_EXP; e++) if (e != e0 && logit[e] > l1) { l1 = logit[e]; e1 = e; }
        float w0 = 1.f / (1.f + __expf(l1 - l0));
        float w1 = 1.f - w0;
        int p0 = atomicAdd(&counts[e0], 1);
        int p1 = atomicAdd(&counts[e1], 1);
        row_token[e0 * N_TOK + p0] = n;  row_weight[e0 * N_TOK + p0] = w0;
        row_token[e1 * N_TOK + p1] = n;  row_weight[e1 * N_TOK + p1] = w1;
        slot_e[n * 2 + 0] = e0;  slot_pos[n * 2 + 0] = p0;
        slot_e[n * 2 + 1] = e1;  slot_pos[n * 2 + 1] = p1;
    }
}

// ---------------- Scan: exclusive prefix over 8 counts ----------------
__global__ void scan_kernel(const int* __restrict__ counts, int* __restrict__ offsets)
{
    if (threadIdx.x == 0 && blockIdx.x == 0) {
        int acc = 0;
        for (int e = 0; e < N_EXP; e++) { offsets[e] = acc; acc += counts[e]; }
    }
}

// ---------------- Up GEMM (grouped, m97 structure): act = silu(X @ w1[e]^T) ----
// 128x128 tile, BK=64, single-buffer LDS [128][64] unpadded, global_load_lds 16B
__global__ __launch_bounds__(256) void up_gemm_kernel(
    const unsigned short* __restrict__ x_bf, const unsigned short* __restrict__ w1_bf,
    const int* __restrict__ counts, const int* __restrict__ offsets,
    const int* __restrict__ row_token,
    unsigned short* __restrict__ act)
{
    const int e = blockIdx.z;
    const int cnt = counts[e];
    const int mTile = blockIdx.y;
    if (mTile * 128 >= cnt) return;
    const int fTile = blockIdx.x;
    const int off = offsets[e];

    __shared__ __align__(16) unsigned short As[128 * 64];
    __shared__ __align__(16) unsigned short Bs[128 * 64];

    const int tid = threadIdx.x;
    const int lane = tid & 63;
    const int wave = tid >> 6;
    const int wm = (wave >> 1) * 64, wn = (wave & 1) * 64;

    // staging geometry: 16 chunks of 1KB per tile; wave w owns chunks w*4..w*4+3.
    // chunk c covers rows c*8..c*8+7; lane l -> row c*8 + (l>>3), col elems (l&7)*8.
    const unsigned short* aSrc[4];
    const unsigned short* bSrc[4];
#pragma unroll
    for (int j = 0; j < 4; j++) {
        const int row_local = wave * 32 + j * 8 + (lane >> 3);
        const int pos = mTile * 128 + row_local;
        const int tok = row_token[e * N_TOK + min(pos, cnt - 1)];
        aSrc[j] = x_bf + (size_t)tok * H_DIM + (lane & 7) * 8;
        bSrc[j] = w1_bf + ((size_t)e * F_DIM + fTile * 128 + row_local) * H_DIM + (lane & 7) * 8;
    }

    f32x4 acc[4][4];
#pragma unroll
    for (int i = 0; i < 4; i++)
#pragma unroll
        for (int j = 0; j < 4; j++) acc[i][j] = (f32x4)(0.f);

    const int NKT = H_DIM / BK;   // 16
    for (int kt = 0; kt < NKT; kt++) {
        const int koff = kt * BK;
#pragma unroll
        for (int j = 0; j < 4; j++) {
            gload16(aSrc[j] + koff, As + (wave * 4 + j) * 512);
            gload16(bSrc[j] + koff, Bs + (wave * 4 + j) * 512);
        }
        __syncthreads();   // implicit vmcnt(0) drains the LDS-bound loads
#pragma unroll
        for (int kk = 0; kk < BK / 32; kk++) {
            const int kloc = kk * 32 + (lane >> 4) * 8;
            bf16x8 af[4], bfr[4];
#pragma unroll
            for (int i = 0; i < 4; i++)
                af[i] = *(const bf16x8*)(As + (wm + i * 16 + (lane & 15)) * 64 + kloc);
#pragma unroll
            for (int i = 0; i < 4; i++)
                bfr[i] = *(const bf16x8*)(Bs + (wn + i * 16 + (lane & 15)) * 64 + kloc);
#pragma unroll
            for (int i = 0; i < 4; i++)
#pragma unroll
                for (int j = 0; j < 4; j++)
                    acc[i][j] = __builtin_amdgcn_mfma_f32_16x16x32_bf16(af[i], bfr[j], acc[i][j], 0, 0, 0);
        }
        __syncthreads();
    }

    // epilogue: silu + bf16 store (C/D layout: col=lane&15, row=(lane>>4)*4+reg)
#pragma unroll
    for (int i = 0; i < 4; i++) {
        const int mrow = wm + i * 16 + ((lane >> 4) << 2);
#pragma unroll
        for (int r = 0; r < 4; r++) {
            const int m = mTile * 128 + mrow + r;
            if (m < cnt) {
#pragma unroll
                for (int j = 0; j < 4; j++) {
                    float v = acc[i][j][r];
                    float s = v / (1.f + __expf(-v));
                    int col = fTile * 128 + wn + j * 16 + (lane & 15);
                    act[(size_t)(off + m) * F_DIM + col] = f2bf(s);
                }
            }
        }
    }
}

// ---------------- Down GEMM (grouped, split-K=2, m97 structure) ---------------
__global__ __launch_bounds__(256) void down_gemm_kernel(
    const unsigned short* __restrict__ act, const unsigned short* __restrict__ w2_bf,
    const int* __restrict__ counts, const int* __restrict__ offsets,
    const float* __restrict__ row_weight,
    float* __restrict__ out_partial)   // [KSPLIT][NSLOT][H_DIM]
{
    const int e  = blockIdx.z & (N_EXP - 1);
    const int ks = blockIdx.z >> 3;
    const int cnt = counts[e];
    const int mTile = blockIdx.y;
    if (mTile * 128 >= cnt) return;
    const int hTile = blockIdx.x;
    const int off = offsets[e];
    const int kbase = ks * KHALF;

    __shared__ __align__(16) unsigned short As[128 * 64];
    __shared__ __align__(16) unsigned short Bs[128 * 64];

    const int tid = threadIdx.x;
    const int lane = tid & 63;
    const int wave = tid >> 6;
    const int wm = (wave >> 1) * 64, wn = (wave & 1) * 64;

    const unsigned short* aSrc[4];
    const unsigned short* bSrc[4];
#pragma unroll
    for (int j = 0; j < 4; j++) {
        const int row_local = wave * 32 + j * 8 + (lane >> 3);
        const int slot = off + min(mTile * 128 + row_local, cnt - 1);
        aSrc[j] = act + (size_t)slot * F_DIM + kbase + (lane & 7) * 8;
        bSrc[j] = w2_bf + ((size_t)e * H_DIM + hTile * 128 + row_local) * F_DIM + kbase + (lane & 7) * 8;
    }

    f32x4 acc[4][4];
#pragma unroll
    for (int i = 0; i < 4; i++)
#pragma unroll
        for (int j = 0; j < 4; j++) acc[i][j] = (f32x4)(0.f);

    const int NKT = KHALF / BK;   // 22
    for (int kt = 0; kt < NKT; kt++) {
        const int koff = kt * BK;
#pragma unroll
        for (int j = 0; j < 4; j++) {
            gload16(aSrc[j] + koff, As + (wave * 4 + j) * 512);
            gload16(bSrc[j] + koff, Bs + (wave * 4 + j) * 512);
        }
        __syncthreads();
#pragma unroll
        for (int kk = 0; kk < BK / 32; kk++) {
            const int kloc = kk * 32 + (lane >> 4) * 8;
            bf16x8 af[4], bfr[4];
#pragma unroll
            for (int i = 0; i < 4; i++)
                af[i] = *(const bf16x8*)(As + (wm + i * 16 + (lane & 15)) * 64 + kloc);
#pragma unroll
            for (int i = 0; i < 4; i++)
                bfr[i] = *(const bf16x8*)(Bs + (wn + i * 16 + (lane & 15)) * 64 + kloc);
#pragma unroll
            for (int i = 0; i < 4; i++)
#pragma unroll
                for (int j = 0; j < 4; j++)
                    acc[i][j] = __builtin_amdgcn_mfma_f32_16x16x32_bf16(af[i], bfr[j], acc[i][j], 0, 0, 0);
        }
        __syncthreads();
    }

    float* obase = out_partial + (size_t)ks * NSLOT * H_DIM;
#pragma unroll
    for (int i = 0; i < 4; i++) {
        const int mrow = wm + i * 16 + ((lane >> 4) << 2);
#pragma unroll
        for (int r = 0; r < 4; r++) {
            const int m = mTile * 128 + mrow + r;
            if (m < cnt) {
                const float w = row_weight[e * N_TOK + m];
#pragma unroll
                for (int j = 0; j < 4; j++) {
                    int col = hTile * 128 + wn + j * 16 + (lane & 15);
                    obase[(size_t)(off + m) * H_DIM + col] = w * acc[i][j][r];
                }
            }
        }
    }
}

// ---------------- Combine: y[n] = sum over 2 slots x 2 K-splits ---------------
__global__ __launch_bounds__(256) void combine_kernel(
    const float* __restrict__ out_partial, const int* __restrict__ offsets,
    const int* __restrict__ slot_e, const int* __restrict__ slot_pos,
    float* __restrict__ out)
{
    const int n = blockIdx.x;
    const int r0 = offsets[slot_e[n * 2 + 0]] + slot_pos[n * 2 + 0];
    const int r1 = offsets[slot_e[n * 2 + 1]] + slot_pos[n * 2 + 1];
    const int t = threadIdx.x;
    const float* p0 = out_partial;
    const float* p1 = out_partial + (size_t)NSLOT * H_DIM;
    const float4 a = *(const float4*)(p0 + (size_t)r0 * H_DIM + t * 4);
    const float4 b = *(const float4*)(p1 + (size_t)r0 * H_DIM + t * 4);
    const float4 c = *(const float4*)(p0 + (size_t)r1 * H_DIM + t * 4);
    const float4 d = *(const float4*)(p1 + (size_t)r1 * H_DIM + t * 4);
    float4 s;
    s.x = (a.x + b.x) + (c.x + d.x);
    s.y = (a.y + b.y) + (c.y + d.y);
    s.z = (a.z + b.z) + (c.z + d.z);
    s.w = (a.w + b.w) + (c.w + d.w);
    *(float4*)(out + (size_t)n * H_DIM + t * 4) = s;
}

extern "C" void kernel_launch(void* const* d_in, const int* in_sizes, int n_in,
                              void* d_out, int out_size, void* d_ws, size_t ws_size,
                              hipStream_t stream) {
    const float* x      = (const float*)d_in[0];
    const float* gate_w = (const float*)d_in[1];
    const float* w1     = (const float*)d_in[2];
    const float* w2     = (const float*)d_in[3];
    float* out = (float*)d_out;

    char* ws = (char*)d_ws;
    size_t o = 0;
    auto alloc = [&](size_t bytes) -> void* {
        void* p = ws + o;
        o = (o + bytes + 255) & ~(size_t)255;
        return p;
    };
    int*   counts     = (int*)  alloc(N_EXP * sizeof(int));
    int*   offsets    = (int*)  alloc(N_EXP * sizeof(int));
    int*   row_token  = (int*)  alloc((size_t)N_EXP * N_TOK * sizeof(int));
    float* row_weight = (float*)alloc((size_t)N_EXP * N_TOK * sizeof(float));
    int*   slot_e     = (int*)  alloc((size_t)N_TOK * 2 * sizeof(int));
    int*   slot_pos   = (int*)  alloc((size_t)N_TOK * 2 * sizeof(int));
    unsigned short* act = (unsigned short*)alloc((size_t)NSLOT * F_DIM * sizeof(unsigned short));
    float* out_partial = (float*)alloc((size_t)KSPLIT * NSLOT * H_DIM * sizeof(float));
    unsigned short* x_bf  = (unsigned short*)alloc((size_t)N_TOK * H_DIM * sizeof(unsigned short));
    unsigned short* w1_bf = (unsigned short*)alloc((size_t)N_EXP * F_DIM * H_DIM * sizeof(unsigned short));
    unsigned short* w2_bf = (unsigned short*)alloc((size_t)N_EXP * H_DIM * F_DIM * sizeof(unsigned short));

    hipMemsetAsync(counts, 0, N_EXP * sizeof(int), stream);

    router_kernel<<<N_TOK / 4, 256, 0, stream>>>(x, gate_w, counts, row_token, row_weight, slot_e, slot_pos);
    scan_kernel<<<1, 64, 0, stream>>>(counts, offsets);
    convert_all_kernel<<<2048, 256, 0, stream>>>(x, w1, w2, x_bf, w1_bf, w2_bf);
    up_gemm_kernel<<<dim3(F_DIM / 128, N_TOK / 128, N_EXP), 256, 0, stream>>>(
        x_bf, w1_bf, counts, offsets, row_token, act);
    down_gemm_kernel<<<dim3(H_DIM / 128, N_TOK / 128, N_EXP * KSPLIT), 256, 0, stream>>>(
        act, w2_bf, counts, offsets, row_weight, out_partial);
    combine_kernel<<<N_TOK, 256, 0, stream>>>(out_partial, offsets, slot_e, slot_pos, out);
}